// Round 1
// baseline (200.014 us; speedup 1.0000x reference)
//
#include <hip/hip_runtime.h>

#define BB 256
#define SS 512
#define VOCAB 50000
#define EMB_D 300
#define POS_MAX 512
#define POS_D 16
#define CNN_OUT 50
#define KW 5
#define NCLASS 10
#define C_IN 332            // EMB_D + 2*POS_D
#define KO 256              // padded (k,o) columns; ko = k*50+o valid for ko<250

// ---------------- K0: relayout conv_w -> W_re[c][256], zero ymax ----------------
__global__ __launch_bounds__(256) void k_prep(const float* __restrict__ conv_w,
                                              float* __restrict__ W_re,
                                              float* __restrict__ ymax) {
    int idx = blockIdx.x * 256 + threadIdx.x;
    const int total_w = C_IN * KO;
    if (idx < total_w) {
        int c = idx >> 8;
        int j = idx & 255;
        float v = 0.f;
        if (j < KW * CNN_OUT) {
            int kk = j / CNN_OUT, o = j % CNN_OUT;
            v = conv_w[o * (C_IN * KW) + c * KW + kk];
        }
        W_re[idx] = v;
    } else if (idx < total_w + BB * CNN_OUT) {
        ymax[idx - total_w] = 0.f;   // relu >= 0, so 0 is the identity for the max
    }
}

// ---------------- K1: nearest-entity distances ----------------
__global__ __launch_bounds__(512) void k_dist(const int* __restrict__ tokens,
                                              const int* __restrict__ e1p,
                                              const int* __restrict__ e2p,
                                              int* __restrict__ d1,
                                              int* __restrict__ d2) {
    __shared__ int cnt1, cnt2;
    __shared__ int lst1[SS], lst2[SS];
    int b = blockIdx.x, s = threadIdx.x;
    if (s == 0) { cnt1 = 0; cnt2 = 0; }
    __syncthreads();
    int tok = tokens[b * SS + s];
    int e1 = *e1p, e2 = *e2p;
    if (tok == e1) lst1[atomicAdd(&cnt1, 1)] = s;
    if (tok == e2) lst2[atomicAdd(&cnt2, 1)] = s;
    __syncthreads();
    int dd1 = POS_MAX - 1;
    int n1 = cnt1;
    for (int i = 0; i < n1; ++i) dd1 = min(dd1, abs(s - lst1[i]));
    int dd2 = POS_MAX - 1;
    int n2 = cnt2;
    for (int i = 0; i < n2; ++i) dd2 = min(dd2, abs(s - lst2[i]));
    d1[b * SS + s] = dd1;
    d2[b * SS + s] = dd2;
}

// ---------------- K2: projection GEMM P[t][ko] = sum_c E[t,c] * W_re[c][ko] ----------------
#define T_TILE 32
__global__ __launch_bounds__(256) void k_proj(const float* __restrict__ E,
                                              const float* __restrict__ W_re,
                                              float* __restrict__ P,
                                              int* __restrict__ rowzero) {
    __shared__ float Elds[T_TILE][EMB_D + 4];   // [32][304] = 38.9 KB
    int tid = threadIdx.x;
    int t0 = blockIdx.x * T_TILE;
    int lane = tid & 63, wv = tid >> 6;

    // cooperative load: wave wv loads rows wv, wv+4, ...
    for (int r = wv; r < T_TILE; r += 4) {
        int t = t0 + r;
        const float* src = E + (size_t)t * EMB_D;
        for (int c = lane; c < EMB_D; c += 64)
            Elds[r][c] = (t < VOCAB) ? src[c] : 0.f;
    }
    __syncthreads();

    // rowzero: all-zero embedding row check (pad mask)
    for (int i = 0; i < T_TILE / 4; ++i) {
        int r = wv * (T_TILE / 4) + i;
        bool nz = false;
        #pragma unroll
        for (int p = 0; p < 5; ++p) {
            int c = lane + p * 64;
            if (c < EMB_D) nz |= (Elds[r][c] != 0.f);
        }
        unsigned long long m = __ballot(nz);
        if (lane == 0) {
            int t = t0 + r;
            if (t < VOCAB) rowzero[t] = (m == 0ULL) ? 1 : 0;
        }
    }

    // register-tiled GEMM: each thread -> 8 tokens x 4 ko columns
    float acc[8][4];
    #pragma unroll
    for (int i = 0; i < 8; ++i)
        #pragma unroll
        for (int q = 0; q < 4; ++q) acc[i][q] = 0.f;

    const float4* W4 = (const float4*)W_re;     // row c: W4[c*64 + jq]
    int jq = lane, tq = wv;
    #pragma unroll 4
    for (int c = 0; c < EMB_D; ++c) {
        float4 w = W4[c * 64 + jq];
        #pragma unroll
        for (int i = 0; i < 8; ++i) {
            float e = Elds[tq * 8 + i][c];
            acc[i][0] += e * w.x;
            acc[i][1] += e * w.y;
            acc[i][2] += e * w.z;
            acc[i][3] += e * w.w;
        }
    }
    #pragma unroll
    for (int i = 0; i < 8; ++i) {
        int t = t0 + tq * 8 + i;
        if (t < VOCAB) {
            float4 v = make_float4(acc[i][0], acc[i][1], acc[i][2], acc[i][3]);
            ((float4*)(P + (size_t)t * KO))[jq] = v;
        }
    }
}

// ---------------- K2b: positional projection tables ----------------
__global__ __launch_bounds__(256) void k_pos(const float* __restrict__ pos,
                                             const float* __restrict__ W_re,
                                             float* __restrict__ P1,
                                             float* __restrict__ P2) {
    int d = blockIdx.x;     // 512
    int j = threadIdx.x;    // 256
    __shared__ float prow[POS_D];
    if (j < POS_D) prow[j] = pos[d * POS_D + j];
    __syncthreads();
    float a1 = 0.f, a2 = 0.f;
    #pragma unroll
    for (int cc = 0; cc < POS_D; ++cc) {
        float pv = prow[cc];
        a1 += pv * W_re[(EMB_D + cc) * KO + j];
        a2 += pv * W_re[(EMB_D + POS_D + cc) * KO + j];
    }
    P1[d * KO + j] = a1;
    P2[d * KO + j] = a2;
}

// ---------------- K3: conv-as-gather-add + relu + maxpool (atomicMax) ----------------
__global__ __launch_bounds__(64) void k_conv(const int* __restrict__ tokens,
                                             const int* __restrict__ d1,
                                             const int* __restrict__ d2,
                                             const int* __restrict__ rowzero,
                                             const float* __restrict__ P,
                                             const float* __restrict__ P1,
                                             const float* __restrict__ P2,
                                             const float* __restrict__ conv_b,
                                             float* __restrict__ ymax) {
    int b = blockIdx.x >> 5, sb = blockIdx.x & 31;
    int s0 = sb * 16;
    int lane = threadIdx.x;
    int o = lane < CNN_OUT ? lane : CNN_OUT - 1;
    float bias = conv_b[o];
    float m = 0.f;                       // relu floor
    const int* trow = tokens + b * SS;
    const int* d1row = d1 + b * SS;
    const int* d2row = d2 + b * SS;
    for (int s = s0; s < s0 + 16; ++s) {
        float y = 0.f;
        #pragma unroll
        for (int k = 0; k < KW; ++k) {
            int sp = s + k - 2;
            if (sp < 0 || sp >= SS) continue;
            int t = trow[sp];
            float v = P[(size_t)t * KO + k * CNN_OUT + o];
            if (!rowzero[t]) {
                v += P1[d1row[sp] * KO + k * CNN_OUT + o];
                v += P2[d2row[sp] * KO + k * CNN_OUT + o];
            }
            y += v;
        }
        m = fmaxf(m, y + bias);
    }
    if (lane < CNN_OUT)
        atomicMax((int*)ymax + b * CNN_OUT + lane, __float_as_int(m));
}

// ---------------- K4: FC ----------------
__global__ __launch_bounds__(64) void k_fc(const float* __restrict__ ymax,
                                           const float* __restrict__ fc_w,
                                           const float* __restrict__ fc_b,
                                           float* __restrict__ out) {
    int b = blockIdx.x, n = threadIdx.x;
    if (n < NCLASS) {
        float a = fc_b[n];
        #pragma unroll
        for (int o = 0; o < CNN_OUT; ++o)
            a += ymax[b * CNN_OUT + o] * fc_w[n * CNN_OUT + o];
        out[b * NCLASS + n] = a;
    }
}

extern "C" void kernel_launch(void* const* d_in, const int* in_sizes, int n_in,
                              void* d_out, int out_size, void* d_ws, size_t ws_size,
                              hipStream_t stream) {
    const int*   tokens  = (const int*)  d_in[0];
    const float* embed   = (const float*)d_in[1];
    const float* pos     = (const float*)d_in[2];
    const float* conv_w  = (const float*)d_in[3];
    const float* conv_b  = (const float*)d_in[4];
    const float* fc_w    = (const float*)d_in[5];
    const float* fc_b    = (const float*)d_in[6];
    const int*   e1p     = (const int*)  d_in[7];
    const int*   e2p     = (const int*)  d_in[8];
    float* out = (float*)d_out;

    char* ws = (char*)d_ws;
    size_t off = 0;
    float* W_re   = (float*)(ws + off); off += (size_t)C_IN * KO * 4;        // 339,968
    float* P      = (float*)(ws + off); off += (size_t)VOCAB * KO * 4;       // 51,200,000
    float* P1     = (float*)(ws + off); off += (size_t)POS_MAX * KO * 4;     // 524,288
    float* P2     = (float*)(ws + off); off += (size_t)POS_MAX * KO * 4;
    int*   d1     = (int*)  (ws + off); off += (size_t)BB * SS * 4;
    int*   d2     = (int*)  (ws + off); off += (size_t)BB * SS * 4;
    int*   rowz   = (int*)  (ws + off); off += (size_t)VOCAB * 4;
    float* ymax   = (float*)(ws + off); off += (size_t)BB * CNN_OUT * 4;
    (void)ws_size; (void)in_sizes; (void)n_in; (void)out_size;

    // K0: weight relayout + ymax zero-init (every launch: atomicMax state must reset)
    {
        int total = C_IN * KO + BB * CNN_OUT;
        hipLaunchKernelGGL(k_prep, dim3((total + 255) / 256), dim3(256), 0, stream,
                           conv_w, W_re, ymax);
    }
    // K1: distances
    hipLaunchKernelGGL(k_dist, dim3(BB), dim3(SS), 0, stream, tokens, e1p, e2p, d1, d2);
    // K2: projection GEMM + rowzero
    hipLaunchKernelGGL(k_proj, dim3((VOCAB + T_TILE - 1) / T_TILE), dim3(256), 0, stream,
                       embed, W_re, P, rowz);
    // K2b: positional tables
    hipLaunchKernelGGL(k_pos, dim3(POS_MAX), dim3(256), 0, stream, pos, W_re, P1, P2);
    // K3: gather-add conv + relu + maxpool
    hipLaunchKernelGGL(k_conv, dim3(BB * (SS / 16)), dim3(64), 0, stream,
                       tokens, d1, d2, rowz, P, P1, P2, conv_b, ymax);
    // K4: FC
    hipLaunchKernelGGL(k_fc, dim3(BB), dim3(64), 0, stream, ymax, fc_w, fc_b, out);
}

// Round 2
// 122.651 us; speedup vs baseline: 1.6308x; 1.6308x over previous
//
#include <hip/hip_runtime.h>

typedef __attribute__((ext_vector_type(8))) short short8;
typedef __attribute__((ext_vector_type(4))) float floatx4;

#define BB 256
#define SS 512
#define VOCAB 50000
#define EMB_D 300
#define POS_MAX 512
#define POS_D 16
#define CNN_OUT 50
#define KW 5
#define NCLASS 10
#define C_IN 332            // EMB_D + 2*POS_D
#define KO 256              // padded (k,o) columns; ko = k*50+o valid for ko<250
#define NKS 10              // K-steps: 10 x 32 = 320 (K=300 zero-padded)
#define ELDS_STRIDE 328     // bf16 elems per LDS row (300 -> 328: 4-bank row advance)

__device__ __forceinline__ unsigned short f2bf(float x) {
    unsigned u = __float_as_uint(x);
    u += 0x7FFF + ((u >> 16) & 1);      // RNE
    return (unsigned short)(u >> 16);
}

// ---------------- K0: pack conv_w -> Wf (MFMA B-fragment-linear bf16), zero ymax ----------------
// Wf flat index: ((ks*16 + nb)*64 + lane)*8 + j  holds  W[c = ks*32+(lane>>4)*8+j][col = nb*16+(lane&15)]
__global__ __launch_bounds__(256) void k_prep(const float* __restrict__ conv_w,
                                              unsigned short* __restrict__ Wf,
                                              float* __restrict__ ymax) {
    int idx = blockIdx.x * 256 + threadIdx.x;
    const int NWF = NKS * 16 * 64 * 8;   // 81920
    if (idx < NWF) {
        int j = idx & 7, l = (idx >> 3) & 63, nb = (idx >> 9) & 15, ks = idx >> 13;
        int c = ks * 32 + ((l >> 4) << 3) + j;
        int col = nb * 16 + (l & 15);
        float v = 0.f;
        if (c < EMB_D && col < KW * CNN_OUT) {
            int kk = col / CNN_OUT, o = col % CNN_OUT;
            v = conv_w[o * (C_IN * KW) + c * KW + kk];
        }
        Wf[idx] = f2bf(v);
    } else if (idx < NWF + BB * CNN_OUT) {
        ymax[idx - NWF] = 0.f;   // relu >= 0, so 0 is the identity for the max
    }
}

// ---------------- K1: nearest-entity distances ----------------
__global__ __launch_bounds__(512) void k_dist(const int* __restrict__ tokens,
                                              const int* __restrict__ e1p,
                                              const int* __restrict__ e2p,
                                              int* __restrict__ d1,
                                              int* __restrict__ d2) {
    __shared__ int cnt1, cnt2;
    __shared__ int lst1[SS], lst2[SS];
    int b = blockIdx.x, s = threadIdx.x;
    if (s == 0) { cnt1 = 0; cnt2 = 0; }
    __syncthreads();
    int tok = tokens[b * SS + s];
    int e1 = *e1p, e2 = *e2p;
    if (tok == e1) lst1[atomicAdd(&cnt1, 1)] = s;
    if (tok == e2) lst2[atomicAdd(&cnt2, 1)] = s;
    __syncthreads();
    int dd1 = POS_MAX - 1;
    int n1 = cnt1;
    for (int i = 0; i < n1; ++i) dd1 = min(dd1, abs(s - lst1[i]));
    int dd2 = POS_MAX - 1;
    int n2 = cnt2;
    for (int i = 0; i < n2; ++i) dd2 = min(dd2, abs(s - lst2[i]));
    d1[b * SS + s] = dd1;
    d2[b * SS + s] = dd2;
}

// ---------------- K2: MFMA projection GEMM P[t][ko] = sum_c E[t,c]*W[c,ko] ----------------
// Block: 256 thr = 4 waves; tile 64 tokens x 256 cols; wave w -> cols w*64..+63.
// Per wave: 4x4 fragments of 16x16, K-loop 10 steps of 32.
__global__ __launch_bounds__(256) void k_proj(const float* __restrict__ E,
                                              const unsigned short* __restrict__ Wf,
                                              float* __restrict__ P,
                                              int* __restrict__ rowzero) {
    __shared__ short Elds[64][ELDS_STRIDE];   // 41,984 B
    int tid = threadIdx.x;
    int lane = tid & 63, w = tid >> 6;
    int t0 = blockIdx.x * 64;

    // ---- stage E rows -> bf16 LDS (4 threads per row, float4 loads) ----
    int r = tid >> 2, q = tid & 3;
    int t = t0 + r;
    bool nz = false;
    const float4* src = (const float4*)(E + (size_t)t * EMB_D);
    #pragma unroll 1
    for (int i = 0; i < 19; ++i) {
        int c4 = q + i * 4;
        if (c4 < 75) {
            float4 v = (t < VOCAB) ? src[c4] : make_float4(0.f, 0.f, 0.f, 0.f);
            nz |= (v.x != 0.f) | (v.y != 0.f) | (v.z != 0.f) | (v.w != 0.f);
            unsigned lo = ((unsigned)f2bf(v.y) << 16) | f2bf(v.x);
            unsigned hi = ((unsigned)f2bf(v.w) << 16) | f2bf(v.z);
            *(uint2*)&Elds[r][c4 * 4] = make_uint2(lo, hi);
        }
    }
    // zero-pad K columns 300..319 (as 10 dwords per row, split across the 4 threads)
    {
        int base = q * 3;
        #pragma unroll
        for (int j = 0; j < 3; ++j) {
            int u = base + j;
            if (u < 10) *(unsigned*)&Elds[r][300 + u * 2] = 0u;
        }
    }
    // rowzero via ballot (4 bits per row within this wave)
    {
        unsigned long long m = __ballot(nz);
        if (q == 0 && t < VOCAB) {
            int rl = r & 15;
            rowzero[t] = (((m >> (rl * 4)) & 0xFULL) == 0ULL) ? 1 : 0;
        }
    }
    __syncthreads();

    // ---- MFMA main loop ----
    floatx4 acc[4][4];
    #pragma unroll
    for (int mm = 0; mm < 4; ++mm)
        #pragma unroll
        for (int nn = 0; nn < 4; ++nn) acc[mm][nn] = (floatx4)0.f;

    int arow = lane & 15, achunk = lane >> 4;
    const short8* Bp = (const short8*)Wf;
    #pragma unroll 1
    for (int ks = 0; ks < NKS; ++ks) {
        short8 a[4], b[4];
        #pragma unroll
        for (int mm = 0; mm < 4; ++mm)
            a[mm] = *(const short8*)&Elds[mm * 16 + arow][ks * 32 + achunk * 8];
        #pragma unroll
        for (int nn = 0; nn < 4; ++nn)
            b[nn] = Bp[(ks * 16 + (w * 4 + nn)) * 64 + lane];
        #pragma unroll
        for (int mm = 0; mm < 4; ++mm)
            #pragma unroll
            for (int nn = 0; nn < 4; ++nn)
                acc[mm][nn] = __builtin_amdgcn_mfma_f32_16x16x32_bf16(a[mm], b[nn], acc[mm][nn], 0, 0, 0);
    }

    // ---- store D: col=lane&15, row=(lane>>4)*4+reg ----
    int drow = (lane >> 4) * 4, dcol = lane & 15;
    #pragma unroll
    for (int mm = 0; mm < 4; ++mm) {
        #pragma unroll
        for (int rg = 0; rg < 4; ++rg) {
            int tt = t0 + mm * 16 + drow + rg;
            if (tt < VOCAB) {
                float* dst = P + (size_t)tt * KO + w * 64 + dcol;
                #pragma unroll
                for (int nn = 0; nn < 4; ++nn)
                    dst[nn * 16] = acc[mm][nn][rg];
            }
        }
    }
}

// ---------------- K2b: positional projection tables (reads conv_w directly) ----------------
__global__ __launch_bounds__(256) void k_pos(const float* __restrict__ pos,
                                             const float* __restrict__ conv_w,
                                             float* __restrict__ P1,
                                             float* __restrict__ P2) {
    int d = blockIdx.x;     // 512
    int j = threadIdx.x;    // 256
    __shared__ float prow[POS_D];
    if (j < POS_D) prow[j] = pos[d * POS_D + j];
    __syncthreads();
    float a1 = 0.f, a2 = 0.f;
    if (j < KW * CNN_OUT) {
        int kk = j / CNN_OUT, o = j % CNN_OUT;
        const float* wb = conv_w + o * (C_IN * KW) + kk;
        #pragma unroll
        for (int cc = 0; cc < POS_D; ++cc) {
            float pv = prow[cc];
            a1 += pv * wb[(EMB_D + cc) * KW];
            a2 += pv * wb[(EMB_D + POS_D + cc) * KW];
        }
    }
    P1[d * KO + j] = a1;
    P2[d * KO + j] = a2;
}

// ---------------- K3: conv-as-gather-add + relu + maxpool (atomicMax) ----------------
__global__ __launch_bounds__(64) void k_conv(const int* __restrict__ tokens,
                                             const int* __restrict__ d1,
                                             const int* __restrict__ d2,
                                             const int* __restrict__ rowzero,
                                             const float* __restrict__ P,
                                             const float* __restrict__ P1,
                                             const float* __restrict__ P2,
                                             const float* __restrict__ conv_b,
                                             float* __restrict__ ymax) {
    int b = blockIdx.x >> 5, sb = blockIdx.x & 31;
    int s0 = sb * 16;
    int lane = threadIdx.x;
    int o = lane < CNN_OUT ? lane : CNN_OUT - 1;
    float bias = conv_b[o];
    float m = 0.f;                       // relu floor
    const int* trow = tokens + b * SS;
    const int* d1row = d1 + b * SS;
    const int* d2row = d2 + b * SS;
    for (int s = s0; s < s0 + 16; ++s) {
        float y = 0.f;
        #pragma unroll
        for (int k = 0; k < KW; ++k) {
            int sp = s + k - 2;
            if (sp < 0 || sp >= SS) continue;
            int t = trow[sp];
            float v = P[(size_t)t * KO + k * CNN_OUT + o];
            if (!rowzero[t]) {
                v += P1[d1row[sp] * KO + k * CNN_OUT + o];
                v += P2[d2row[sp] * KO + k * CNN_OUT + o];
            }
            y += v;
        }
        m = fmaxf(m, y + bias);
    }
    if (lane < CNN_OUT)
        atomicMax((int*)ymax + b * CNN_OUT + lane, __float_as_int(m));
}

// ---------------- K4: FC ----------------
__global__ __launch_bounds__(64) void k_fc(const float* __restrict__ ymax,
                                           const float* __restrict__ fc_w,
                                           const float* __restrict__ fc_b,
                                           float* __restrict__ out) {
    int b = blockIdx.x, n = threadIdx.x;
    if (n < NCLASS) {
        float a = fc_b[n];
        #pragma unroll
        for (int o = 0; o < CNN_OUT; ++o)
            a += ymax[b * CNN_OUT + o] * fc_w[n * CNN_OUT + o];
        out[b * NCLASS + n] = a;
    }
}

extern "C" void kernel_launch(void* const* d_in, const int* in_sizes, int n_in,
                              void* d_out, int out_size, void* d_ws, size_t ws_size,
                              hipStream_t stream) {
    const int*   tokens  = (const int*)  d_in[0];
    const float* embed   = (const float*)d_in[1];
    const float* pos     = (const float*)d_in[2];
    const float* conv_w  = (const float*)d_in[3];
    const float* conv_b  = (const float*)d_in[4];
    const float* fc_w    = (const float*)d_in[5];
    const float* fc_b    = (const float*)d_in[6];
    const int*   e1p     = (const int*)  d_in[7];
    const int*   e2p     = (const int*)  d_in[8];
    float* out = (float*)d_out;

    char* ws = (char*)d_ws;
    size_t off = 0;
    unsigned short* Wf = (unsigned short*)(ws + off); off += (size_t)NKS * 16 * 64 * 8 * 2; // 163,840
    float* P      = (float*)(ws + off); off += (size_t)VOCAB * KO * 4;       // 51,200,000
    float* P1     = (float*)(ws + off); off += (size_t)POS_MAX * KO * 4;
    float* P2     = (float*)(ws + off); off += (size_t)POS_MAX * KO * 4;
    int*   d1     = (int*)  (ws + off); off += (size_t)BB * SS * 4;
    int*   d2     = (int*)  (ws + off); off += (size_t)BB * SS * 4;
    int*   rowz   = (int*)  (ws + off); off += (size_t)VOCAB * 4;
    float* ymax   = (float*)(ws + off); off += (size_t)BB * CNN_OUT * 4;
    (void)ws_size; (void)in_sizes; (void)n_in; (void)out_size;

    // K0: weight pack + ymax zero-init (every launch: atomicMax state must reset)
    {
        int total = NKS * 16 * 64 * 8 + BB * CNN_OUT;
        hipLaunchKernelGGL(k_prep, dim3((total + 255) / 256), dim3(256), 0, stream,
                           conv_w, Wf, ymax);
    }
    // K1: distances
    hipLaunchKernelGGL(k_dist, dim3(BB), dim3(512), 0, stream, tokens, e1p, e2p, d1, d2);
    // K2: MFMA projection GEMM + rowzero
    hipLaunchKernelGGL(k_proj, dim3((VOCAB + 63) / 64), dim3(256), 0, stream,
                       embed, Wf, P, rowz);
    // K2b: positional tables
    hipLaunchKernelGGL(k_pos, dim3(POS_MAX), dim3(256), 0, stream, pos, conv_w, P1, P2);
    // K3: gather-add conv + relu + maxpool
    hipLaunchKernelGGL(k_conv, dim3(BB * (SS / 16)), dim3(64), 0, stream,
                       tokens, d1, d2, rowz, P, P1, P2, conv_b, ymax);
    // K4: FC
    hipLaunchKernelGGL(k_fc, dim3(BB), dim3(64), 0, stream, ymax, fc_w, fc_b, out);
}

// Round 3
// 105.824 us; speedup vs baseline: 1.8901x; 1.1590x over previous
//
#include <hip/hip_runtime.h>

typedef __attribute__((ext_vector_type(8))) short short8;
typedef __attribute__((ext_vector_type(4))) float floatx4;

#define BB 256
#define SS 512
#define VOCAB 50000
#define EMB_D 300
#define POS_MAX 512
#define POS_D 16
#define CNN_OUT 50
#define KW 5
#define NCLASS 10
#define C_IN 332            // EMB_D + 2*POS_D
#define CPAD 352            // per-window K padding: 11 x 32
#define NKS 55              // K-steps: 5 windows x 11
#define FROWS 68            // 64 outputs + 2+2 halo
#define FSTR 360            // LDS row stride in bf16 (720B -> 20-bank row advance, ~2-way)
#define NWF (NKS * 4 * 64 * 8)   // 112640 packed B elems

__device__ __forceinline__ unsigned short f2bf(float x) {
    unsigned u = __float_as_uint(x);
    u += 0x7FFF + ((u >> 16) & 1);      // RNE
    return (unsigned short)(u >> 16);
}

// ---------------- K0: pack conv_w -> Wf (im2col B-fragment-linear bf16), zero ymax -------
// Wf flat index ((ks*4 + nb)*64 + l)*8 + j holds W_im2col[K=(k=ks/11, c=(ks%11)*32+(l>>4)*8+j)]
//                                              [col = nb*16 + (l&15)]  (= conv_w[col][c][k])
__global__ __launch_bounds__(256) void k_prep(const float* __restrict__ conv_w,
                                              unsigned short* __restrict__ Wf,
                                              float* __restrict__ ymax) {
    int idx = blockIdx.x * 256 + threadIdx.x;
    if (idx < NWF) {
        int j = idx & 7, l = (idx >> 3) & 63, nb = (idx >> 9) & 3, ks = idx >> 11;
        int k = ks / 11;
        int c = (ks % 11) * 32 + ((l >> 4) << 3) + j;
        int col = nb * 16 + (l & 15);
        float v = 0.f;
        if (c < C_IN && col < CNN_OUT)
            v = conv_w[col * (C_IN * KW) + c * KW + k];
        Wf[idx] = f2bf(v);
    } else if (idx < NWF + BB * CNN_OUT) {
        ymax[idx - NWF] = 0.f;   // relu >= 0, so 0 is the identity for the max
    }
}

// ---------------- K1: nearest-entity distances ----------------
__global__ __launch_bounds__(512) void k_dist(const int* __restrict__ tokens,
                                              const int* __restrict__ e1p,
                                              const int* __restrict__ e2p,
                                              int* __restrict__ d1,
                                              int* __restrict__ d2) {
    __shared__ int cnt1, cnt2;
    __shared__ int lst1[SS], lst2[SS];
    int b = blockIdx.x, s = threadIdx.x;
    if (s == 0) { cnt1 = 0; cnt2 = 0; }
    __syncthreads();
    int tok = tokens[b * SS + s];
    int e1 = *e1p, e2 = *e2p;
    if (tok == e1) lst1[atomicAdd(&cnt1, 1)] = s;
    if (tok == e2) lst2[atomicAdd(&cnt2, 1)] = s;
    __syncthreads();
    int dd1 = POS_MAX - 1;
    int n1 = cnt1;
    for (int i = 0; i < n1; ++i) dd1 = min(dd1, abs(s - lst1[i]));
    int dd2 = POS_MAX - 1;
    int n2 = cnt2;
    for (int i = 0; i < n2; ++i) dd2 = min(dd2, abs(s - lst2[i]));
    d1[b * SS + s] = dd1;
    d2[b * SS + s] = dd2;
}

// ---------------- K2: fused im2col conv + relu + maxpool ----------------
// Block: 256 thr = 4 waves; tile = 64 output positions x 64 cols (50 valid) of one sentence.
// Stage 68 feature rows (E | pos1 | pos2, bf16) in LDS once, then 55 MFMA K-steps, no
// per-step barriers. Wave w owns output-column fragment nn=w.
__global__ __launch_bounds__(256, 3) void k_fused(const int* __restrict__ tokens,
                                                  const int* __restrict__ d1,
                                                  const int* __restrict__ d2,
                                                  const float* __restrict__ E,
                                                  const float* __restrict__ pos,
                                                  const unsigned short* __restrict__ Wf,
                                                  const float* __restrict__ conv_b,
                                                  float* __restrict__ ymax) {
    __shared__ short F[FROWS * FSTR];   // 48,960 B
    int tid = threadIdx.x, lane = tid & 63, w = tid >> 6;
    int b = blockIdx.x >> 3, sb = blockIdx.x & 7;
    int s0 = sb * 64;

    // ---- stage feature rows: 4 threads per row ----
    int q = tid & 3;
    for (int rr = tid >> 2; rr < FROWS; rr += 64) {
        int sp = s0 - 2 + rr;
        bool valid = (sp >= 0 && sp < SS);
        int t = valid ? tokens[b * SS + sp] : 0;
        const float4* src = (const float4*)(E + (size_t)t * EMB_D);
        bool nz = false;
        #pragma unroll 1
        for (int i = 0; i < 19; ++i) {
            int c4 = q + i * 4;
            if (c4 < 75) {
                float4 v = valid ? src[c4] : make_float4(0.f, 0.f, 0.f, 0.f);
                nz |= (v.x != 0.f) | (v.y != 0.f) | (v.z != 0.f) | (v.w != 0.f);
                unsigned lo = ((unsigned)f2bf(v.y) << 16) | f2bf(v.x);
                unsigned hi = ((unsigned)f2bf(v.w) << 16) | f2bf(v.z);
                *(uint2*)&F[rr * FSTR + c4 * 4] = make_uint2(lo, hi);
            }
        }
        // pad-row mask: all-zero fp32 embedding row (4-lane ballot group per row)
        unsigned long long bal = __ballot(nz);
        bool rowz = (((bal >> (4 * (lane >> 2))) & 0xFULL) == 0ULL);
        if (q < 2) {
            // pos features: cols 300..315 (d1) / 316..331 (d2)
            int dd = valid ? (q == 0 ? d1[b * SS + sp] : d2[b * SS + sp]) : 0;
            const float4* ps = (const float4*)(pos + dd * POS_D);
            int cbase = EMB_D + q * POS_D;
            #pragma unroll
            for (int i = 0; i < 4; ++i) {
                float4 v = (valid && !rowz) ? ps[i] : make_float4(0.f, 0.f, 0.f, 0.f);
                unsigned lo = ((unsigned)f2bf(v.y) << 16) | f2bf(v.x);
                unsigned hi = ((unsigned)f2bf(v.w) << 16) | f2bf(v.z);
                *(uint2*)&F[rr * FSTR + cbase + i * 4] = make_uint2(lo, hi);
            }
        } else {
            // zero K-pad cols 332..351 (read by MFMA as window tail)
            int cbase = C_IN + (q - 2) * 10;
            #pragma unroll
            for (int i = 0; i < 5; ++i)
                *(unsigned*)&F[rr * FSTR + cbase + i * 2] = 0u;
        }
    }
    __syncthreads();

    // ---- MFMA: 4 m-frags x 1 n-frag (nn = w), K = 5 windows x 11 steps of 32 ----
    floatx4 acc[4];
    #pragma unroll
    for (int mm = 0; mm < 4; ++mm) acc[mm] = (floatx4)0.f;

    int arow = lane & 15, achunk = (lane >> 4) * 8;
    const short8* Bp = (const short8*)Wf;
    #pragma unroll
    for (int k = 0; k < KW; ++k) {
        #pragma unroll
        for (int kc = 0; kc < 11; ++kc) {
            int ks = k * 11 + kc;
            short8 bfrag = Bp[(ks * 4 + w) * 64 + lane];
            const short* abase = &F[(arow + k) * FSTR + kc * 32 + achunk];
            #pragma unroll
            for (int mm = 0; mm < 4; ++mm) {
                short8 afrag = *(const short8*)(abase + mm * 16 * FSTR);
                acc[mm] = __builtin_amdgcn_mfma_f32_16x16x32_bf16(afrag, bfrag, acc[mm], 0, 0, 0);
            }
        }
    }

    // ---- bias + relu + max over rows + atomicMax ----
    int col = w * 16 + (lane & 15);
    float bias = (col < CNN_OUT) ? conv_b[col] : 0.f;
    float m = 0.f;                       // relu floor
    #pragma unroll
    for (int mm = 0; mm < 4; ++mm)
        #pragma unroll
        for (int rg = 0; rg < 4; ++rg)
            m = fmaxf(m, acc[mm][rg] + bias);
    m = fmaxf(m, __shfl_xor(m, 16));
    m = fmaxf(m, __shfl_xor(m, 32));
    if ((lane >> 4) == 0 && col < CNN_OUT)
        atomicMax((int*)ymax + b * CNN_OUT + col, __float_as_int(m));
}

// ---------------- K4: FC ----------------
__global__ __launch_bounds__(64) void k_fc(const float* __restrict__ ymax,
                                           const float* __restrict__ fc_w,
                                           const float* __restrict__ fc_b,
                                           float* __restrict__ out) {
    int b = blockIdx.x, n = threadIdx.x;
    if (n < NCLASS) {
        float a = fc_b[n];
        #pragma unroll
        for (int o = 0; o < CNN_OUT; ++o)
            a += ymax[b * CNN_OUT + o] * fc_w[n * CNN_OUT + o];
        out[b * NCLASS + n] = a;
    }
}

extern "C" void kernel_launch(void* const* d_in, const int* in_sizes, int n_in,
                              void* d_out, int out_size, void* d_ws, size_t ws_size,
                              hipStream_t stream) {
    const int*   tokens  = (const int*)  d_in[0];
    const float* embed   = (const float*)d_in[1];
    const float* pos     = (const float*)d_in[2];
    const float* conv_w  = (const float*)d_in[3];
    const float* conv_b  = (const float*)d_in[4];
    const float* fc_w    = (const float*)d_in[5];
    const float* fc_b    = (const float*)d_in[6];
    const int*   e1p     = (const int*)  d_in[7];
    const int*   e2p     = (const int*)  d_in[8];
    float* out = (float*)d_out;

    char* ws = (char*)d_ws;
    size_t off = 0;
    unsigned short* Wf = (unsigned short*)(ws + off); off += (size_t)NWF * 2;     // 225,280
    int*   d1     = (int*)  (ws + off); off += (size_t)BB * SS * 4;
    int*   d2     = (int*)  (ws + off); off += (size_t)BB * SS * 4;
    float* ymax   = (float*)(ws + off); off += (size_t)BB * CNN_OUT * 4;
    (void)ws_size; (void)in_sizes; (void)n_in; (void)out_size;

    // K0: weight pack + ymax zero-init (every launch: atomicMax state must reset)
    {
        int total = NWF + BB * CNN_OUT;
        hipLaunchKernelGGL(k_prep, dim3((total + 255) / 256), dim3(256), 0, stream,
                           conv_w, Wf, ymax);
    }
    // K1: distances
    hipLaunchKernelGGL(k_dist, dim3(BB), dim3(512), 0, stream, tokens, e1p, e2p, d1, d2);
    // K2: fused im2col conv + relu + maxpool
    hipLaunchKernelGGL(k_fused, dim3(BB * (SS / 64)), dim3(256), 0, stream,
                       tokens, d1, d2, embed, pos, Wf, conv_b, ymax);
    // K4: FC
    hipLaunchKernelGGL(k_fc, dim3(BB), dim3(64), 0, stream, ymax, fc_w, fc_b, out);
}

// Round 4
// 78.507 us; speedup vs baseline: 2.5477x; 1.3480x over previous
//
#include <hip/hip_runtime.h>

typedef __attribute__((ext_vector_type(8))) short short8;
typedef __attribute__((ext_vector_type(4))) float floatx4;

#define BB 256
#define SS 512
#define VOCAB 50000
#define EMB_D 300
#define POS_MAX 512
#define POS_D 16
#define CNN_OUT 50
#define KW 5
#define NCLASS 10
#define C_IN 332            // EMB_D + 2*POS_D
#define CPAD 352            // per-window K padding: 11 x 32
#define NKS 55              // K-steps: 5 windows x 11
#define FROWS 68            // 64 outputs + 2+2 halo
#define FSTR 360            // LDS row stride in bf16 (720B -> 20-bank row advance)
#define NWF (NKS * 4 * 64 * 8)   // 112640 packed B elems

__device__ __forceinline__ unsigned short f2bf(float x) {
    unsigned u = __float_as_uint(x);
    u += 0x7FFF + ((u >> 16) & 1);      // RNE
    return (unsigned short)(u >> 16);
}

// ---------------- K0: pack conv_w -> Wf (im2col B-fragment-linear bf16), zero ymax -------
// Wf flat index ((ks*4 + nb)*64 + l)*8 + j holds W_im2col[K=(k=ks/11, c=(ks%11)*32+(l>>4)*8+j)]
//                                              [col = nb*16 + (l&15)]  (= conv_w[col][c][k])
__global__ __launch_bounds__(256) void k_prep(const float* __restrict__ conv_w,
                                              unsigned short* __restrict__ Wf,
                                              float* __restrict__ ymax) {
    int idx = blockIdx.x * 256 + threadIdx.x;
    if (idx < NWF) {
        int j = idx & 7, l = (idx >> 3) & 63, nb = (idx >> 9) & 3, ks = idx >> 11;
        int k = ks / 11;
        int c = (ks % 11) * 32 + ((l >> 4) << 3) + j;
        int col = nb * 16 + (l & 15);
        float v = 0.f;
        if (c < C_IN && col < CNN_OUT)
            v = conv_w[col * (C_IN * KW) + c * KW + k];
        Wf[idx] = f2bf(v);
    } else if (idx < NWF + BB * CNN_OUT) {
        ymax[idx - NWF] = 0.f;   // relu >= 0, so 0 is the identity for the max
    }
}

// ---------------- K1: nearest-entity distances ----------------
__global__ __launch_bounds__(512) void k_dist(const int* __restrict__ tokens,
                                              const int* __restrict__ e1p,
                                              const int* __restrict__ e2p,
                                              int* __restrict__ d1,
                                              int* __restrict__ d2) {
    __shared__ int cnt1, cnt2;
    __shared__ int lst1[SS], lst2[SS];
    int b = blockIdx.x, s = threadIdx.x;
    if (s == 0) { cnt1 = 0; cnt2 = 0; }
    __syncthreads();
    int tok = tokens[b * SS + s];
    int e1 = *e1p, e2 = *e2p;
    if (tok == e1) lst1[atomicAdd(&cnt1, 1)] = s;
    if (tok == e2) lst2[atomicAdd(&cnt2, 1)] = s;
    __syncthreads();
    int dd1 = POS_MAX - 1;
    int n1 = cnt1;
    for (int i = 0; i < n1; ++i) dd1 = min(dd1, abs(s - lst1[i]));
    int dd2 = POS_MAX - 1;
    int n2 = cnt2;
    for (int i = 0; i < n2; ++i) dd2 = min(dd2, abs(s - lst2[i]));
    d1[b * SS + s] = dd1;
    d2[b * SS + s] = dd2;
}

// ---------------- K2: fused im2col conv + relu + maxpool ----------------
// Block: 256 thr = 4 waves; tile = 64 output positions x 64 cols (50 valid) of one sentence.
// Staging: 8 threads/row, all loads batched into registers first (MLP), then cvt+ds_write.
// Then 55 MFMA K-steps with no per-step barriers. Wave w owns output-column fragment nn=w.
__global__ __launch_bounds__(256, 3) void k_fused(const int* __restrict__ tokens,
                                                  const int* __restrict__ d1,
                                                  const int* __restrict__ d2,
                                                  const float* __restrict__ E,
                                                  const float* __restrict__ pos,
                                                  const unsigned short* __restrict__ Wf,
                                                  const float* __restrict__ conv_b,
                                                  float* __restrict__ ymax) {
    __shared__ short F[FROWS * FSTR];   // 48,960 B
    int tid = threadIdx.x, lane = tid & 63, w = tid >> 6;
    int b = blockIdx.x >> 3, sb = blockIdx.x & 7;
    int s0 = sb * 64;

    // ---- stage feature rows: 8 threads per row, 3 row-passes (32 rows/pass) ----
    int q = tid & 7;
    for (int rr = tid >> 3; rr < FROWS; rr += 32) {
        int sp = s0 - 2 + rr;
        bool valid = (sp >= 0 && sp < SS);
        int t = valid ? tokens[b * SS + sp] : 0;
        const float4* src = (const float4*)(E + (size_t)t * EMB_D);

        // phase 1: issue all E loads (10 independent float4s in flight per thread)
        float4 v[10];
        #pragma unroll
        for (int i = 0; i < 10; ++i) {
            int c4 = q + i * 8;
            v[i] = (valid && c4 < 75) ? src[c4] : make_float4(0.f, 0.f, 0.f, 0.f);
        }
        bool nz = false;
        #pragma unroll
        for (int i = 0; i < 10; ++i)
            nz |= (v[i].x != 0.f) | (v[i].y != 0.f) | (v[i].z != 0.f) | (v[i].w != 0.f);

        // phase 2: convert + LDS write
        #pragma unroll
        for (int i = 0; i < 10; ++i) {
            int c4 = q + i * 8;
            if (c4 < 75) {
                unsigned lo = ((unsigned)f2bf(v[i].y) << 16) | f2bf(v[i].x);
                unsigned hi = ((unsigned)f2bf(v[i].w) << 16) | f2bf(v[i].z);
                *(uint2*)&F[rr * FSTR + c4 * 4] = make_uint2(lo, hi);
            }
        }

        // pad-row mask: all-zero fp32 embedding row (8-lane ballot group per row)
        unsigned long long bal = __ballot(nz);
        int g = lane >> 3;
        bool rowz = (((bal >> (g * 8)) & 0xFFULL) == 0ULL);

        if (q < 2) {
            // pos features: cols 300..315 (d1) / 316..331 (d2)
            int dd = valid ? (q == 0 ? d1[b * SS + sp] : d2[b * SS + sp]) : 0;
            const float4* ps = (const float4*)(pos + dd * POS_D);
            int cbase = EMB_D + q * POS_D;
            #pragma unroll
            for (int i = 0; i < 4; ++i) {
                float4 pv = (valid && !rowz) ? ps[i] : make_float4(0.f, 0.f, 0.f, 0.f);
                unsigned lo = ((unsigned)f2bf(pv.y) << 16) | f2bf(pv.x);
                unsigned hi = ((unsigned)f2bf(pv.w) << 16) | f2bf(pv.z);
                *(uint2*)&F[rr * FSTR + cbase + i * 4] = make_uint2(lo, hi);
            }
        } else if (q < 4) {
            // zero K-pad cols 332..351 (read by MFMA as window tail)
            int cbase = C_IN + (q - 2) * 10;
            #pragma unroll
            for (int i = 0; i < 5; ++i)
                *(unsigned*)&F[rr * FSTR + cbase + i * 2] = 0u;
        }
    }
    __syncthreads();

    // ---- MFMA: 4 m-frags x 1 n-frag (nn = w), K = 5 windows x 11 steps of 32 ----
    floatx4 acc[4];
    #pragma unroll
    for (int mm = 0; mm < 4; ++mm) acc[mm] = (floatx4)0.f;

    int arow = lane & 15, achunk = (lane >> 4) * 8;
    const short8* Bp = (const short8*)Wf;
    #pragma unroll
    for (int k = 0; k < KW; ++k) {
        #pragma unroll
        for (int kc = 0; kc < 11; ++kc) {
            int ks = k * 11 + kc;
            short8 bfrag = Bp[(ks * 4 + w) * 64 + lane];
            const short* abase = &F[(arow + k) * FSTR + kc * 32 + achunk];
            #pragma unroll
            for (int mm = 0; mm < 4; ++mm) {
                short8 afrag = *(const short8*)(abase + mm * 16 * FSTR);
                acc[mm] = __builtin_amdgcn_mfma_f32_16x16x32_bf16(afrag, bfrag, acc[mm], 0, 0, 0);
            }
        }
    }

    // ---- bias + relu + max over rows + atomicMax ----
    int col = w * 16 + (lane & 15);
    float bias = (col < CNN_OUT) ? conv_b[col] : 0.f;
    float m = 0.f;                       // relu floor
    #pragma unroll
    for (int mm = 0; mm < 4; ++mm)
        #pragma unroll
        for (int rg = 0; rg < 4; ++rg)
            m = fmaxf(m, acc[mm][rg] + bias);
    m = fmaxf(m, __shfl_xor(m, 16));
    m = fmaxf(m, __shfl_xor(m, 32));
    if ((lane >> 4) == 0 && col < CNN_OUT)
        atomicMax((int*)ymax + b * CNN_OUT + col, __float_as_int(m));
}

// ---------------- K4: FC ----------------
__global__ __launch_bounds__(64) void k_fc(const float* __restrict__ ymax,
                                           const float* __restrict__ fc_w,
                                           const float* __restrict__ fc_b,
                                           float* __restrict__ out) {
    int b = blockIdx.x, n = threadIdx.x;
    if (n < NCLASS) {
        float a = fc_b[n];
        #pragma unroll
        for (int o = 0; o < CNN_OUT; ++o)
            a += ymax[b * CNN_OUT + o] * fc_w[n * CNN_OUT + o];
        out[b * NCLASS + n] = a;
    }
}

extern "C" void kernel_launch(void* const* d_in, const int* in_sizes, int n_in,
                              void* d_out, int out_size, void* d_ws, size_t ws_size,
                              hipStream_t stream) {
    const int*   tokens  = (const int*)  d_in[0];
    const float* embed   = (const float*)d_in[1];
    const float* pos     = (const float*)d_in[2];
    const float* conv_w  = (const float*)d_in[3];
    const float* conv_b  = (const float*)d_in[4];
    const float* fc_w    = (const float*)d_in[5];
    const float* fc_b    = (const float*)d_in[6];
    const int*   e1p     = (const int*)  d_in[7];
    const int*   e2p     = (const int*)  d_in[8];
    float* out = (float*)d_out;

    char* ws = (char*)d_ws;
    size_t off = 0;
    unsigned short* Wf = (unsigned short*)(ws + off); off += (size_t)NWF * 2;     // 225,280
    int*   d1     = (int*)  (ws + off); off += (size_t)BB * SS * 4;
    int*   d2     = (int*)  (ws + off); off += (size_t)BB * SS * 4;
    float* ymax   = (float*)(ws + off); off += (size_t)BB * CNN_OUT * 4;
    (void)ws_size; (void)in_sizes; (void)n_in; (void)out_size;

    // K0: weight pack + ymax zero-init (every launch: atomicMax state must reset)
    {
        int total = NWF + BB * CNN_OUT;
        hipLaunchKernelGGL(k_prep, dim3((total + 255) / 256), dim3(256), 0, stream,
                           conv_w, Wf, ymax);
    }
    // K1: distances
    hipLaunchKernelGGL(k_dist, dim3(BB), dim3(512), 0, stream, tokens, e1p, e2p, d1, d2);
    // K2: fused im2col conv + relu + maxpool
    hipLaunchKernelGGL(k_fused, dim3(BB * (SS / 64)), dim3(256), 0, stream,
                       tokens, d1, d2, embed, pos, Wf, conv_b, ymax);
    // K4: FC
    hipLaunchKernelGGL(k_fc, dim3(BB), dim3(64), 0, stream, ymax, fc_w, fc_b, out);
}

// Round 5
// 69.038 us; speedup vs baseline: 2.8971x; 1.1371x over previous
//
#include <hip/hip_runtime.h>

typedef __attribute__((ext_vector_type(8))) short short8;
typedef __attribute__((ext_vector_type(4))) float floatx4;

#define BB 256
#define SS 512
#define VOCAB 50000
#define EMB_D 300
#define POS_MAX 512
#define POS_D 16
#define CNN_OUT 50
#define KW 5
#define NCLASS 10
#define C_IN 332            // EMB_D + 2*POS_D
#define CPAD 352            // per-window K padding: 11 x 32
#define NKS 55              // K-steps: 5 windows x 11
#define FROWS 68            // 64 outputs + 2+2 halo
#define FSTR 392            // LDS row stride in bf16 (784B == 16 mod 128 -> balanced bank walk)
#define NWF (NKS * 4 * 64 * 8)   // 112640 packed B elems

__device__ __forceinline__ unsigned short f2bf(float x) {
    unsigned u = __float_as_uint(x);
    u += 0x7FFF + ((u >> 16) & 1);      // RNE
    return (unsigned short)(u >> 16);
}

// ---------------- K0: pack conv_w -> Wf (im2col B-fragment-linear bf16), zero ymax -------
// Wf flat index ((ks*4 + nb)*64 + l)*8 + j holds W_im2col[K=(k=ks/11, c=(ks%11)*32+(l>>4)*8+j)]
//                                              [col = nb*16 + (l&15)]  (= conv_w[col][c][k])
__global__ __launch_bounds__(256) void k_prep(const float* __restrict__ conv_w,
                                              unsigned short* __restrict__ Wf,
                                              float* __restrict__ ymax) {
    int idx = blockIdx.x * 256 + threadIdx.x;
    if (idx < NWF) {
        int j = idx & 7, l = (idx >> 3) & 63, nb = (idx >> 9) & 3, ks = idx >> 11;
        int k = ks / 11;
        int c = (ks % 11) * 32 + ((l >> 4) << 3) + j;
        int col = nb * 16 + (l & 15);
        float v = 0.f;
        if (c < C_IN && col < CNN_OUT)
            v = conv_w[col * (C_IN * KW) + c * KW + k];
        Wf[idx] = f2bf(v);
    } else if (idx < NWF + BB * CNN_OUT) {
        ymax[idx - NWF] = 0.f;   // relu >= 0, so 0 is the identity for the max
    }
}

// ---------------- K1: nearest-entity distances ----------------
__global__ __launch_bounds__(512) void k_dist(const int* __restrict__ tokens,
                                              const int* __restrict__ e1p,
                                              const int* __restrict__ e2p,
                                              int* __restrict__ d1,
                                              int* __restrict__ d2) {
    __shared__ int cnt1, cnt2;
    __shared__ int lst1[SS], lst2[SS];
    int b = blockIdx.x, s = threadIdx.x;
    if (s == 0) { cnt1 = 0; cnt2 = 0; }
    __syncthreads();
    int tok = tokens[b * SS + s];
    int e1 = *e1p, e2 = *e2p;
    if (tok == e1) lst1[atomicAdd(&cnt1, 1)] = s;
    if (tok == e2) lst2[atomicAdd(&cnt2, 1)] = s;
    __syncthreads();
    int dd1 = POS_MAX - 1;
    int n1 = cnt1;
    for (int i = 0; i < n1; ++i) dd1 = min(dd1, abs(s - lst1[i]));
    int dd2 = POS_MAX - 1;
    int n2 = cnt2;
    for (int i = 0; i < n2; ++i) dd2 = min(dd2, abs(s - lst2[i]));
    d1[b * SS + s] = dd1;
    d2[b * SS + s] = dd2;
}

// ---------------- K2: fused im2col conv + relu + maxpool ----------------
// Block: 256 thr = 4 waves; tile = 64 output positions x 64 cols (50 valid) of one sentence.
// Staging: 8 threads/row, loads batched into registers (MLP), then cvt+ds_write.
// MFMA: waves split K (14/14/14/13 of 55 steps); per step 4 A ds_reads + 4 B global loads
// feed 16 MFMAs. Cross-wave reduction of partials in 2 LDS rounds, then epilogue.
__global__ __launch_bounds__(256, 3) void k_fused(const int* __restrict__ tokens,
                                                  const int* __restrict__ d1,
                                                  const int* __restrict__ d2,
                                                  const float* __restrict__ E,
                                                  const float* __restrict__ pos,
                                                  const unsigned short* __restrict__ Wf,
                                                  const float* __restrict__ conv_b,
                                                  float* __restrict__ ymax) {
    __shared__ __align__(16) short F[FROWS * FSTR];   // 53,312 B
    int tid = threadIdx.x, lane = tid & 63, w = tid >> 6;
    int b = blockIdx.x >> 3, sb = blockIdx.x & 7;
    int s0 = sb * 64;

    // ---- stage feature rows: 8 threads per row, 32 rows/pass ----
    int q = tid & 7;
    for (int rr = tid >> 3; rr < FROWS; rr += 32) {
        int sp = s0 - 2 + rr;
        bool valid = (sp >= 0 && sp < SS);
        int t = valid ? tokens[b * SS + sp] : 0;
        const float4* src = (const float4*)(E + (size_t)t * EMB_D);

        // phase 1: issue all E loads (10 independent float4s in flight per thread)
        float4 v[10];
        #pragma unroll
        for (int i = 0; i < 10; ++i) {
            int c4 = q + i * 8;
            v[i] = (valid && c4 < 75) ? src[c4] : make_float4(0.f, 0.f, 0.f, 0.f);
        }
        bool nz = false;
        #pragma unroll
        for (int i = 0; i < 10; ++i)
            nz |= (v[i].x != 0.f) | (v[i].y != 0.f) | (v[i].z != 0.f) | (v[i].w != 0.f);

        // phase 2: convert + LDS write
        #pragma unroll
        for (int i = 0; i < 10; ++i) {
            int c4 = q + i * 8;
            if (c4 < 75) {
                unsigned lo = ((unsigned)f2bf(v[i].y) << 16) | f2bf(v[i].x);
                unsigned hi = ((unsigned)f2bf(v[i].w) << 16) | f2bf(v[i].z);
                *(uint2*)&F[rr * FSTR + c4 * 4] = make_uint2(lo, hi);
            }
        }

        // pad-row mask: all-zero fp32 embedding row (8-lane ballot group per row)
        unsigned long long bal = __ballot(nz);
        int g = lane >> 3;
        bool rowz = (((bal >> (g * 8)) & 0xFFULL) == 0ULL);

        if (q < 2) {
            // pos features: cols 300..315 (d1) / 316..331 (d2)
            int dd = valid ? (q == 0 ? d1[b * SS + sp] : d2[b * SS + sp]) : 0;
            const float4* ps = (const float4*)(pos + dd * POS_D);
            int cbase = EMB_D + q * POS_D;
            #pragma unroll
            for (int i = 0; i < 4; ++i) {
                float4 pv = (valid && !rowz) ? ps[i] : make_float4(0.f, 0.f, 0.f, 0.f);
                unsigned lo = ((unsigned)f2bf(pv.y) << 16) | f2bf(pv.x);
                unsigned hi = ((unsigned)f2bf(pv.w) << 16) | f2bf(pv.z);
                *(uint2*)&F[rr * FSTR + cbase + i * 4] = make_uint2(lo, hi);
            }
        } else if (q < 4) {
            // zero K-pad cols 332..351 (read by MFMA as window tail)
            int cbase = C_IN + (q - 2) * 10;
            #pragma unroll
            for (int i = 0; i < 5; ++i)
                *(unsigned*)&F[rr * FSTR + cbase + i * 2] = 0u;
        }
    }
    __syncthreads();

    // ---- MFMA: wave w does K-steps [w*14, min(w*14+14, 55)), all 4x4 fragments ----
    floatx4 acc[4][4];
    #pragma unroll
    for (int mm = 0; mm < 4; ++mm)
        #pragma unroll
        for (int nn = 0; nn < 4; ++nn) acc[mm][nn] = (floatx4)0.f;

    int arow = lane & 15, achunk = (lane >> 4) * 8;
    const short8* Bp = (const short8*)Wf;
    int lo = w * 14;
    int hi = min(lo + 14, NKS);

    short8 bnext[4];
    #pragma unroll
    for (int nb = 0; nb < 4; ++nb)
        bnext[nb] = Bp[(lo * 4 + nb) * 64 + lane];

    for (int ks = lo; ks < hi; ++ks) {
        short8 bfrag[4];
        #pragma unroll
        for (int nb = 0; nb < 4; ++nb) bfrag[nb] = bnext[nb];
        if (ks + 1 < hi) {
            #pragma unroll
            for (int nb = 0; nb < 4; ++nb)
                bnext[nb] = Bp[((ks + 1) * 4 + nb) * 64 + lane];
        }
        int k = ks / 11, kc = ks % 11;
        const short* abase = &F[(arow + k) * FSTR + kc * 32 + achunk];
        #pragma unroll
        for (int mm = 0; mm < 4; ++mm) {
            short8 afrag = *(const short8*)(abase + mm * 16 * FSTR);
            #pragma unroll
            for (int nn = 0; nn < 4; ++nn)
                acc[mm][nn] = __builtin_amdgcn_mfma_f32_16x16x32_bf16(afrag, bfrag[nn], acc[mm][nn], 0, 0, 0);
        }
    }

    // ---- cross-wave reduction: 2 rounds of 32KB through F ----
    // slot = src*8 + i*4 + nn  (i = mm within round); each slot = 64 lanes x 16B
    __syncthreads();                      // all A-reads done; F reusable
    float* R = (float*)F;
    floatx4 red[4];
    #pragma unroll
    for (int round = 0; round < 2; ++round) {
        #pragma unroll
        for (int i = 0; i < 2; ++i)
            #pragma unroll
            for (int nn = 0; nn < 4; ++nn)
                *(floatx4*)&R[((w * 8 + i * 4 + nn) * 64 + lane) * 4] = acc[round * 2 + i][nn];
        __syncthreads();
        #pragma unroll
        for (int i = 0; i < 2; ++i) {
            floatx4 s0 = *(floatx4*)&R[((0 * 8 + i * 4 + w) * 64 + lane) * 4];
            floatx4 s1 = *(floatx4*)&R[((1 * 8 + i * 4 + w) * 64 + lane) * 4];
            floatx4 s2 = *(floatx4*)&R[((2 * 8 + i * 4 + w) * 64 + lane) * 4];
            floatx4 s3 = *(floatx4*)&R[((3 * 8 + i * 4 + w) * 64 + lane) * 4];
            red[round * 2 + i] = (s0 + s1) + (s2 + s3);
        }
        __syncthreads();
    }

    // ---- bias + relu + max over rows + atomicMax (wave w owns cols w*16..w*16+15) ----
    int col = w * 16 + (lane & 15);
    float bias = (col < CNN_OUT) ? conv_b[col] : 0.f;
    float m = 0.f;                       // relu floor
    #pragma unroll
    for (int mi = 0; mi < 4; ++mi)
        #pragma unroll
        for (int rg = 0; rg < 4; ++rg)
            m = fmaxf(m, red[mi][rg] + bias);
    m = fmaxf(m, __shfl_xor(m, 16));
    m = fmaxf(m, __shfl_xor(m, 32));
    if ((lane >> 4) == 0 && col < CNN_OUT)
        atomicMax((int*)ymax + b * CNN_OUT + col, __float_as_int(m));
}

// ---------------- K4: FC ----------------
__global__ __launch_bounds__(64) void k_fc(const float* __restrict__ ymax,
                                           const float* __restrict__ fc_w,
                                           const float* __restrict__ fc_b,
                                           float* __restrict__ out) {
    int b = blockIdx.x, n = threadIdx.x;
    if (n < NCLASS) {
        float a = fc_b[n];
        #pragma unroll
        for (int o = 0; o < CNN_OUT; ++o)
            a += ymax[b * CNN_OUT + o] * fc_w[n * CNN_OUT + o];
        out[b * NCLASS + n] = a;
    }
}

extern "C" void kernel_launch(void* const* d_in, const int* in_sizes, int n_in,
                              void* d_out, int out_size, void* d_ws, size_t ws_size,
                              hipStream_t stream) {
    const int*   tokens  = (const int*)  d_in[0];
    const float* embed   = (const float*)d_in[1];
    const float* pos     = (const float*)d_in[2];
    const float* conv_w  = (const float*)d_in[3];
    const float* conv_b  = (const float*)d_in[4];
    const float* fc_w    = (const float*)d_in[5];
    const float* fc_b    = (const float*)d_in[6];
    const int*   e1p     = (const int*)  d_in[7];
    const int*   e2p     = (const int*)  d_in[8];
    float* out = (float*)d_out;

    char* ws = (char*)d_ws;
    size_t off = 0;
    unsigned short* Wf = (unsigned short*)(ws + off); off += (size_t)NWF * 2;     // 225,280
    int*   d1     = (int*)  (ws + off); off += (size_t)BB * SS * 4;
    int*   d2     = (int*)  (ws + off); off += (size_t)BB * SS * 4;
    float* ymax   = (float*)(ws + off); off += (size_t)BB * CNN_OUT * 4;
    (void)ws_size; (void)in_sizes; (void)n_in; (void)out_size;

    // K0: weight pack + ymax zero-init (every launch: atomicMax state must reset)
    {
        int total = NWF + BB * CNN_OUT;
        hipLaunchKernelGGL(k_prep, dim3((total + 255) / 256), dim3(256), 0, stream,
                           conv_w, Wf, ymax);
    }
    // K1: distances
    hipLaunchKernelGGL(k_dist, dim3(BB), dim3(512), 0, stream, tokens, e1p, e2p, d1, d2);
    // K2: fused im2col conv + relu + maxpool
    hipLaunchKernelGGL(k_fused, dim3(BB * (SS / 64)), dim3(256), 0, stream,
                       tokens, d1, d2, embed, pos, Wf, conv_b, ymax);
    // K4: FC
    hipLaunchKernelGGL(k_fc, dim3(BB), dim3(64), 0, stream, ymax, fc_w, fc_b, out);
}